// Round 28
// baseline (39.538 us; speedup 1.0000x reference)
//
#include <hip/hip_runtime.h>
#include <stdint.h>

#define BB 64
#define NC 1000       // customers per instance
#define KC 10         // clusters
#define MEMCAP 212    // per-cluster member capacity (mean ~100, 11+ sigma)
#define RCAP 64       // per-cluster route capacity (hard max ~43)
#define BPI 40        // blocks per instance: 10 clusters x 4 quads (lp moved to k_final)

__host__ __device__ inline void threefry2x32(uint32_t k0, uint32_t k1,
                                             uint32_t x0, uint32_t x1,
                                             uint32_t* o0, uint32_t* o1) {
  uint32_t k2 = k0 ^ k1 ^ 0x1BD11BDAu;
  x0 += k0; x1 += k1;
#define TF_R(R) { x0 += x1; x1 = (x1 << (R)) | (x1 >> (32 - (R))); x1 ^= x0; }
  TF_R(13) TF_R(15) TF_R(26) TF_R(6)
  x0 += k1; x1 += k2 + 1u;
  TF_R(17) TF_R(29) TF_R(16) TF_R(24)
  x0 += k2; x1 += k0 + 2u;
  TF_R(13) TF_R(15) TF_R(26) TF_R(6)
  x0 += k0; x1 += k1 + 3u;
  TF_R(17) TF_R(29) TF_R(16) TF_R(24)
  x0 += k1; x1 += k2 + 4u;
  TF_R(13) TF_R(15) TF_R(26) TF_R(6)
  x0 += k2; x1 += k0 + 5u;
#undef TF_R
  *o0 = x0; *o1 = x1;
}

__device__ inline uint32_t rand_bits(uint32_t ks0, uint32_t ks1, uint32_t p) {
  uint32_t a, b; threefry2x32(ks0, ks1, 0u, p, &a, &b); return b;
}

// ---- 16-lane DPP helpers (16-lane group = one DPP row; within any group
// ---- taking a branch, all 16 lanes are active -> row sources valid) ----
template <int CTRL>
__device__ __forceinline__ void dpp_min_step(unsigned long long& comb,
                                             float& x, float& y) {
  int lo = (int)(uint32_t)comb;
  int hi = (int)(uint32_t)(comb >> 32);
  int olo = __builtin_amdgcn_update_dpp(lo, lo, CTRL, 0xf, 0xf, false);
  int ohi = __builtin_amdgcn_update_dpp(hi, hi, CTRL, 0xf, 0xf, false);
  int oxi = __builtin_amdgcn_update_dpp(__float_as_int(x), __float_as_int(x),
                                        CTRL, 0xf, 0xf, false);
  int oyi = __builtin_amdgcn_update_dpp(__float_as_int(y), __float_as_int(y),
                                        CTRL, 0xf, 0xf, false);
  unsigned long long o =
      ((unsigned long long)(uint32_t)ohi << 32) | (uint32_t)olo;
  if (o < comb) { comb = o; x = __int_as_float(oxi); y = __int_as_float(oyi); }
}

template <int CTRL>
__device__ __forceinline__ void dpp_max_step(unsigned long long& pk, float& x) {
  int lo = (int)(uint32_t)pk;
  int hi = (int)(uint32_t)(pk >> 32);
  int olo = __builtin_amdgcn_update_dpp(lo, lo, CTRL, 0xf, 0xf, false);
  int ohi = __builtin_amdgcn_update_dpp(hi, hi, CTRL, 0xf, 0xf, false);
  int oxi = __builtin_amdgcn_update_dpp(__float_as_int(x), __float_as_int(x),
                                        CTRL, 0xf, 0xf, false);
  unsigned long long o =
      ((unsigned long long)(uint32_t)ohi << 32) | (uint32_t)olo;
  if (o > pk) { pk = o; x = __int_as_float(oxi); }
}

template <int CTRL>
__device__ __forceinline__ float dpp_fmax(float x) {
  int o = __builtin_amdgcn_update_dpp(__float_as_int(x), __float_as_int(x),
                                      CTRL, 0xf, 0xf, false);
  return fmaxf(x, __int_as_float(o));
}

template <int CTRL>
__device__ __forceinline__ float dpp_fadd(float x) {
  int o = __builtin_amdgcn_update_dpp(__float_as_int(x), __float_as_int(x),
                                      CTRL, 0xf, 0xf, false);
  return x + __int_as_float(o);
}

// ---------------------------------------------------------------------------
// Kernel S: 16 lanes per customer (proven r12-r27, absmax 2.5). Unchanged.
// ---------------------------------------------------------------------------
__global__ __launch_bounds__(256) void k_sample(
    const float* __restrict__ logits,   // (64,1001,10)
    uint32_t ks0, uint32_t ks1,
    uint8_t* __restrict__ assign,       // (64,1000)
    float* __restrict__ slp) {          // (64,1000)
  int gtid = blockIdx.x * 256 + threadIdx.x;   // 1,024,000 = 4000*256
  int cust = gtid >> 4;
  int k = gtid & 15;
  int b = cust / NC, n = cust - b * NC;
  const float TINY = 1.1754943508222875e-38f;
  bool actk = (k < KC);

  float x = actk ? logits[((size_t)b * 1001 + (size_t)(n + 1)) * KC + k]
                 : -INFINITY;
  float v = -INFINITY;
  if (actk) {
    uint32_t bits = rand_bits(ks0, ks1, (uint32_t)cust * (uint32_t)KC + (uint32_t)k);
    float f = __uint_as_float((bits >> 9) | 0x3f800000u) - 1.0f;
    float u = (f > 0.0f) ? f : TINY;
    float g = -logf(-logf(u));
    v = g + x;
  }
  uint32_t uv = __float_as_uint(v);
  uint32_t key = (uv & 0x80000000u) ? ~uv : (uv | 0x80000000u);
  unsigned long long pk =
      ((unsigned long long)key << 32) | (uint32_t)(15 - k);  // ties -> min k
  float bwx = x;
  dpp_max_step<0xB1>(pk, bwx);
  dpp_max_step<0x4E>(pk, bwx);
  dpp_max_step<0x141>(pk, bwx);
  dpp_max_step<0x140>(pk, bwx);
  int best_k = 15 - (int)(pk & 0xFu);

  float xm = x;
  xm = dpp_fmax<0xB1>(xm); xm = dpp_fmax<0x4E>(xm);
  xm = dpp_fmax<0x141>(xm); xm = dpp_fmax<0x140>(xm);

  float es = actk ? expf(x - xm) : 0.0f;
  es = dpp_fadd<0xB1>(es); es = dpp_fadd<0x4E>(es);
  es = dpp_fadd<0x141>(es); es = dpp_fadd<0x140>(es);

  if (k == 0) {
    slp[cust] = (bwx - xm) - logf(es);
    assign[cust] = (uint8_t)best_k;
  }
}

// ---------------------------------------------------------------------------
// Kernel R v9: one wave per block; 4 quad blocks per cluster (16-way route
// partition, NN rounds = 1 — r25/r26/r27's winning axis, now at its
// decomposition minimum). lp blocks REMOVED (moved to k_final): pure
// 40-block-per-instance grid. All arithmetic r27-verbatim -> bit-identical
// routes, absmax 2.5.
// ---------------------------------------------------------------------------
__global__ __launch_bounds__(64, 1) void k_route(
    const float* __restrict__ coords,    // (64,1001,2)
    const float* __restrict__ demands,   // (64,1001)
    const float* __restrict__ capacity,  // (64,)
    const uint8_t* __restrict__ assign,  // (64,1000)
    double* __restrict__ pdistc) {       // (64,10,4) per-(cluster,quad) sums
  int b = blockIdx.x / BPI;
  int blk = blockIdx.x % BPI;            // 0..39 = (cluster<<2)|quad
  int lane = threadIdx.x;                // 0..63 (one wave)

  __shared__ float memx[MEMCAP], memy[MEMCAP], demp[MEMCAP];
  __shared__ uint16_t rsw[RCAP], rlw[RCAP];

  int myk = blk >> 2;                    // cluster 0..9
  int qd  = blk & 3;                     // quad 0..3
  const float* cb = coords + (size_t)b * 1001 * 2;
  const float2* cb2 = reinterpret_cast<const float2*>(cb);
  const float* db = demands + (size_t)b * 1001;
  const uint8_t* ab = assign + (size_t)b * NC;
  float cap = capacity[b];
  float dx0 = cb[0], dy0 = cb[1];

  // ---- zero demp (padding correctness for the float4 split walk) ----
#pragma unroll
  for (int t = 0; t < 4; ++t) {
    int i = t * 64 + lane;
    if (i < MEMCAP) demp[i] = 0.0f;
  }

  // ---- wide-load compaction: lane owns customers 16*lane .. 16*lane+15 ----
  int ci0 = lane * 16;
  float X[16], Y[16], D[16];
  uint32_t A[16];
#pragma unroll
  for (int j = 0; j < 16; ++j) { X[j] = 0.0f; Y[j] = 0.0f; D[j] = 0.0f; A[j] = 0xFFu; }

  if (lane < 62) {
    const uint4* ap = reinterpret_cast<const uint4*>(ab + ci0);
    const float4* cp = reinterpret_cast<const float4*>(cb + 2 * ci0);
    const float4* dp = reinterpret_cast<const float4*>(db + ci0);
    uint4 a4 = ap[0];
    float4 c0 = cp[0], c1 = cp[1], c2 = cp[2], c3 = cp[3], c4 = cp[4],
           c5 = cp[5], c6 = cp[6], c7 = cp[7], c8 = cp[8];
    float4 e0 = dp[0], e1 = dp[1], e2 = dp[2], e3 = dp[3], e4 = dp[4];
    A[0]  =  a4.x        & 0xFFu; A[1]  = (a4.x >>  8) & 0xFFu;
    A[2]  = (a4.x >> 16) & 0xFFu; A[3]  = (a4.x >> 24) & 0xFFu;
    A[4]  =  a4.y        & 0xFFu; A[5]  = (a4.y >>  8) & 0xFFu;
    A[6]  = (a4.y >> 16) & 0xFFu; A[7]  = (a4.y >> 24) & 0xFFu;
    A[8]  =  a4.z        & 0xFFu; A[9]  = (a4.z >>  8) & 0xFFu;
    A[10] = (a4.z >> 16) & 0xFFu; A[11] = (a4.z >> 24) & 0xFFu;
    A[12] =  a4.w        & 0xFFu; A[13] = (a4.w >>  8) & 0xFFu;
    A[14] = (a4.w >> 16) & 0xFFu; A[15] = (a4.w >> 24) & 0xFFu;
    X[0]  = c0.z; Y[0]  = c0.w;  X[1]  = c1.x; Y[1]  = c1.y;
    X[2]  = c1.z; Y[2]  = c1.w;  X[3]  = c2.x; Y[3]  = c2.y;
    X[4]  = c2.z; Y[4]  = c2.w;  X[5]  = c3.x; Y[5]  = c3.y;
    X[6]  = c3.z; Y[6]  = c3.w;  X[7]  = c4.x; Y[7]  = c4.y;
    X[8]  = c4.z; Y[8]  = c4.w;  X[9]  = c5.x; Y[9]  = c5.y;
    X[10] = c5.z; Y[10] = c5.w;  X[11] = c6.x; Y[11] = c6.y;
    X[12] = c6.z; Y[12] = c6.w;  X[13] = c7.x; Y[13] = c7.y;
    X[14] = c7.z; Y[14] = c7.w;  X[15] = c8.x; Y[15] = c8.y;
    D[0]  = e0.y; D[1]  = e0.z; D[2]  = e0.w; D[3]  = e1.x;
    D[4]  = e1.y; D[5]  = e1.z; D[6]  = e1.w; D[7]  = e2.x;
    D[8]  = e2.y; D[9]  = e2.z; D[10] = e2.w; D[11] = e3.x;
    D[12] = e3.y; D[13] = e3.z; D[14] = e3.w; D[15] = e4.x;
  } else if (lane == 62) {
#pragma unroll
    for (int j = 0; j < 8; ++j) {
      int ci = 992 + j;
      A[j] = ab[ci];
      float2 c = cb2[ci + 1];
      X[j] = c.x; Y[j] = c.y;
      D[j] = db[ci + 1];
    }
  }

  // ---- rank: per-lane count + 6-step wave exclusive scan ----
  int cnt = 0;
#pragma unroll
  for (int j = 0; j < 16; ++j) cnt += (A[j] == (uint32_t)myk);
  int xs = cnt;
#pragma unroll
  for (int off = 1; off < 64; off <<= 1) {
    int v = __shfl_up(xs, off);
    if (lane >= off) xs += v;
  }
  int pos = xs - cnt;
  int mcount = __shfl(xs, 63);

  // ---- stable scatter (chunk-major = index order) ----
#pragma unroll
  for (int j = 0; j < 16; ++j) {
    if (A[j] == (uint32_t)myk && pos < MEMCAP) {
      memx[pos] = X[j];
      memy[pos] = Y[j];
      demp[pos] = D[j];
      pos++;
    }
  }
  int M = (mcount < MEMCAP) ? mcount : MEMCAP;

  // ---- capacity split: lane-0 float4 walk, 2-deep prefetch ----
  int rcount = 0;
  if (lane == 0 && M > 0) {
    const float4* dp4 = reinterpret_cast<const float4*>(&demp[0]);
    float load = 0.0f;
    int cur = 0, r = 0;
    int trips = (M + 3) >> 2;
    float4 cv = dp4[0];
    float4 nv = dp4[1];
    for (int t = 0; t < trips; ++t) {
      float4 nv2 = dp4[t + 2];
#define SPLIT_E(DV, E)                                                        \
      {                                                                       \
        int j = t * 4 + E;                                                    \
        float d = DV;                                                         \
        if (j == 0) load = d;                                                 \
        else if (load + d > cap) {                                            \
          rsw[r] = (uint16_t)cur; rlw[r] = (uint16_t)(j - cur);               \
          r++; cur = j; load = d;                                             \
        } else load += d;                /* padding d=0: load<=cap -> no-op */\
      }
      SPLIT_E(cv.x, 0) SPLIT_E(cv.y, 1) SPLIT_E(cv.z, 2) SPLIT_E(cv.w, 3)
#undef SPLIT_E
      cv = nv; nv = nv2;
    }
    rsw[r] = (uint16_t)cur;
    rlw[r] = (uint16_t)(M - cur);
    r++;
    rcount = r;
  }
  rcount = __shfl(rcount, 0);

  // ---- NN: this block handles routes r == qd*4 + grp (mod 16) ----
  int lane16 = lane & 15;
  int grp = lane >> 4;
  double gacc = 0.0;

  for (int r = qd * 4 + grp; r < rcount; r += 16) {
    int start = rsw[r];
    int L = rlw[r];
    float px = dx0, py = dy0, racc = 0.0f;

    if (L <= 16) {
      float mx = 0.0f, my = 0.0f;
      bool act = (lane16 < L);
      if (act) { mx = memx[start + lane16]; my = memy[start + lane16]; }
      uint32_t unv = act ? 1u : 0u;
      for (int step = 0; step < L; ++step) {
        float bd = INFINITY, bx = 0.0f, by = 0.0f;
        if (unv) {
          float ddx = mx - px, ddy = my - py;
          bd = sqrtf(ddx * ddx + ddy * ddy);
          bx = mx; by = my;
        }
        unsigned long long comb = unv
            ? ((((unsigned long long)__float_as_uint(bd)) << 32) |
               (unsigned)lane16)
            : ~0ull;
        dpp_min_step<0xB1>(comb, bx, by);
        dpp_min_step<0x4E>(comb, bx, by);
        dpp_min_step<0x141>(comb, bx, by);
        dpp_min_step<0x140>(comb, bx, by);
        int wl = (int)(comb & 0xFFFFFFFFull);
        float best = __uint_as_float((uint32_t)(comb >> 32));
        if (wl == (int)lane16) unv = 0;
        px = bx; py = by;
        racc += best;                    // f32, reference scan order
      }
    } else {
      float mx0 = 0, my0 = 0, mx1 = 0, my1 = 0, mx2 = 0, my2 = 0, mx3 = 0, my3 = 0;
      uint32_t vis = 0;
#define LOADC(c, MX, MY)                                                      \
      { int s = (c) * 16 + lane16;                                            \
        if (s < L) { MX = memx[start + s]; MY = memy[start + s]; }            \
        else vis |= (1u << (c)); }
      LOADC(0, mx0, my0) LOADC(1, mx1, my1) LOADC(2, mx2, my2) LOADC(3, mx3, my3)
#undef LOADC
      for (int step = 0; step < L; ++step) {
        float bd = INFINITY; int bc = -1; float bx = 0, by = 0;
#define CAND(c, MX, MY)                                                       \
        if (!(vis & (1u << (c)))) {                                           \
          float ddx = MX - px, ddy = MY - py;                                 \
          float d = sqrtf(ddx * ddx + ddy * ddy);                             \
          if (d < bd) { bd = d; bc = (c); bx = MX; by = MY; }                 \
        }
        CAND(0, mx0, my0) CAND(1, mx1, my1) CAND(2, mx2, my2) CAND(3, mx3, my3)
#undef CAND
        unsigned long long comb = (bc < 0)
            ? ~0ull
            : (((unsigned long long)__float_as_uint(bd)) << 32) |
              (unsigned)(bc * 16 + lane16);
        dpp_min_step<0xB1>(comb, bx, by);
        dpp_min_step<0x4E>(comb, bx, by);
        dpp_min_step<0x141>(comb, bx, by);
        dpp_min_step<0x140>(comb, bx, by);
        int slot = (int)(comb & 0xFFFFFFFFull);
        float best = __uint_as_float((uint32_t)(comb >> 32));
        int src16 = slot & 15, cu = slot >> 4;
        if (src16 == (int)lane16) vis |= (1u << cu);
        px = bx; py = by;
        racc += best;                    // f32, reference scan order
      }
    }
    float ddx = px - dx0, ddy = py - dy0;
    racc += sqrtf(ddx * ddx + ddy * ddy);
    gacc += (double)racc;
  }

  // ---- wave reduction of the group partials ----
  {
    double t2 = (lane16 == 0) ? gacc : 0.0;
#pragma unroll
    for (int m = 1; m < 64; m <<= 1) t2 += __shfl_xor(t2, m);
    if (lane == 0) pdistc[(b * KC + myk) * 4 + qd] = t2;
  }
}

// ---------------------------------------------------------------------------
// Kernel C v2: lp reduction (moved from k_route) + loss finalize.
// 256 threads: thread (b,q) sums slp[b, q*250 .. q*250+250) via float2 in f64
// (fixed grouping; lp delta ~1e-12 vs r27). Threads 0..63 then combine and
// run the proven shfl loss math.
// ---------------------------------------------------------------------------
__global__ __launch_bounds__(256) void k_final(
    const float* __restrict__ slp,       // (64,1000)
    const double* __restrict__ pdistc,   // (64,10,4)
    float* __restrict__ out) {           // (2,)
  __shared__ double psum[256];
  int tid = threadIdx.x;
  int b = tid >> 2, q = tid & 3;
  {
    const float2* s2 = reinterpret_cast<const float2*>(
        slp + (size_t)b * NC + (size_t)q * 250);   // 250*4B = 1000B, 8B-aligned
    double acc = 0.0;
#pragma unroll 5
    for (int i = 0; i < 125; ++i) {
      float2 v = s2[i];
      acc += (double)v.x + (double)v.y;
    }
    psum[tid] = acc;
  }
  __syncthreads();
  if (tid < 64) {
    double lpv = psum[4 * tid] + psum[4 * tid + 1] +
                 psum[4 * tid + 2] + psum[4 * tid + 3];
    double dd = 0.0;
#pragma unroll
    for (int k = 0; k < KC * 4; ++k) dd += pdistc[tid * KC * 4 + k];
    float df = (float)dd;
    float lf = (float)lpv;
    double m = (double)df;
#pragma unroll
    for (int m2 = 1; m2 < 64; m2 <<= 1) m += __shfl_xor(m, m2);
    double mean = m / 64.0;
    float meanf = (float)mean;
    double li = ((double)df - (double)meanf) * (double)lf;
#pragma unroll
    for (int m2 = 1; m2 < 64; m2 <<= 1) li += __shfl_xor(li, m2);
    if (tid == 0) {
      out[0] = (float)(li / 64.0);
      out[1] = meanf;
    }
  }
}

extern "C" void kernel_launch(void* const* d_in, const int* in_sizes, int n_in,
                              void* d_out, int out_size, void* d_ws, size_t ws_size,
                              hipStream_t stream) {
  const float* logits   = (const float*)d_in[0];  // (64,1001,10)
  const float* coords   = (const float*)d_in[1];  // (64,1001,2)
  const float* demands  = (const float*)d_in[2];  // (64,1001)
  const float* capacity = (const float*)d_in[3];  // (64,)

  uint8_t* ws = (uint8_t*)d_ws;
  double*  pdistc = (double*)(ws);            // 20480 B (64*10*4 doubles)
  uint8_t* assign = (uint8_t*)(ws + 20480);   // 64000 B
  float*   slp    = (float*)(ws + 84480);     // 256000 B (16B-aligned)

  uint32_t ks0, ks1;
  threefry2x32(0u, 42u, 0u, 0u, &ks0, &ks1);   // fold_in(key(42), 0)

  k_sample<<<dim3(BB * NC * 16 / 256), dim3(256), 0, stream>>>(
      logits, ks0, ks1, assign, slp);
  k_route<<<dim3(BB * BPI), dim3(64), 0, stream>>>(
      coords, demands, capacity, assign, pdistc);
  k_final<<<dim3(1), dim3(256), 0, stream>>>(slp, pdistc, (float*)d_out);
}

// Round 29
// 28.314 us; speedup vs baseline: 1.3964x; 1.3964x over previous
//
#include <hip/hip_runtime.h>
#include <stdint.h>

#define BB 64
#define NC 1000       // customers per instance
#define KC 10         // clusters
#define MEMCAP 212    // per-cluster member capacity (mean ~100, 11+ sigma)
#define RCAP 64       // per-cluster route capacity (hard max ~43)
#define BPI 41        // blocks per instance: 10 clusters x 4 quads + 1 lp

__host__ __device__ inline void threefry2x32(uint32_t k0, uint32_t k1,
                                             uint32_t x0, uint32_t x1,
                                             uint32_t* o0, uint32_t* o1) {
  uint32_t k2 = k0 ^ k1 ^ 0x1BD11BDAu;
  x0 += k0; x1 += k1;
#define TF_R(R) { x0 += x1; x1 = (x1 << (R)) | (x1 >> (32 - (R))); x1 ^= x0; }
  TF_R(13) TF_R(15) TF_R(26) TF_R(6)
  x0 += k1; x1 += k2 + 1u;
  TF_R(17) TF_R(29) TF_R(16) TF_R(24)
  x0 += k2; x1 += k0 + 2u;
  TF_R(13) TF_R(15) TF_R(26) TF_R(6)
  x0 += k0; x1 += k1 + 3u;
  TF_R(17) TF_R(29) TF_R(16) TF_R(24)
  x0 += k1; x1 += k2 + 4u;
  TF_R(13) TF_R(15) TF_R(26) TF_R(6)
  x0 += k2; x1 += k0 + 5u;
#undef TF_R
  *o0 = x0; *o1 = x1;
}

__device__ inline uint32_t rand_bits(uint32_t ks0, uint32_t ks1, uint32_t p) {
  uint32_t a, b; threefry2x32(ks0, ks1, 0u, p, &a, &b); return b;
}

// ---- 16-lane DPP helpers (16-lane group = one DPP row; within any group
// ---- taking a branch, all 16 lanes are active -> row sources valid) ----
template <int CTRL>
__device__ __forceinline__ void dpp_min_step(unsigned long long& comb,
                                             float& x, float& y) {
  int lo = (int)(uint32_t)comb;
  int hi = (int)(uint32_t)(comb >> 32);
  int olo = __builtin_amdgcn_update_dpp(lo, lo, CTRL, 0xf, 0xf, false);
  int ohi = __builtin_amdgcn_update_dpp(hi, hi, CTRL, 0xf, 0xf, false);
  int oxi = __builtin_amdgcn_update_dpp(__float_as_int(x), __float_as_int(x),
                                        CTRL, 0xf, 0xf, false);
  int oyi = __builtin_amdgcn_update_dpp(__float_as_int(y), __float_as_int(y),
                                        CTRL, 0xf, 0xf, false);
  unsigned long long o =
      ((unsigned long long)(uint32_t)ohi << 32) | (uint32_t)olo;
  if (o < comb) { comb = o; x = __int_as_float(oxi); y = __int_as_float(oyi); }
}

template <int CTRL>
__device__ __forceinline__ void dpp_max_step(unsigned long long& pk, float& x) {
  int lo = (int)(uint32_t)pk;
  int hi = (int)(uint32_t)(pk >> 32);
  int olo = __builtin_amdgcn_update_dpp(lo, lo, CTRL, 0xf, 0xf, false);
  int ohi = __builtin_amdgcn_update_dpp(hi, hi, CTRL, 0xf, 0xf, false);
  int oxi = __builtin_amdgcn_update_dpp(__float_as_int(x), __float_as_int(x),
                                        CTRL, 0xf, 0xf, false);
  unsigned long long o =
      ((unsigned long long)(uint32_t)ohi << 32) | (uint32_t)olo;
  if (o > pk) { pk = o; x = __int_as_float(oxi); }
}

template <int CTRL>
__device__ __forceinline__ float dpp_fmax(float x) {
  int o = __builtin_amdgcn_update_dpp(__float_as_int(x), __float_as_int(x),
                                      CTRL, 0xf, 0xf, false);
  return fmaxf(x, __int_as_float(o));
}

template <int CTRL>
__device__ __forceinline__ float dpp_fadd(float x) {
  int o = __builtin_amdgcn_update_dpp(__float_as_int(x), __float_as_int(x),
                                      CTRL, 0xf, 0xf, false);
  return x + __int_as_float(o);
}

// ---------------------------------------------------------------------------
// Kernel S: 16 lanes per customer (proven r12-r27, absmax 2.5). Unchanged.
// ---------------------------------------------------------------------------
__global__ __launch_bounds__(256) void k_sample(
    const float* __restrict__ logits,   // (64,1001,10)
    uint32_t ks0, uint32_t ks1,
    uint8_t* __restrict__ assign,       // (64,1000)
    float* __restrict__ slp) {          // (64,1000)
  int gtid = blockIdx.x * 256 + threadIdx.x;   // 1,024,000 = 4000*256
  int cust = gtid >> 4;
  int k = gtid & 15;
  int b = cust / NC, n = cust - b * NC;
  const float TINY = 1.1754943508222875e-38f;
  bool actk = (k < KC);

  float x = actk ? logits[((size_t)b * 1001 + (size_t)(n + 1)) * KC + k]
                 : -INFINITY;
  float v = -INFINITY;
  if (actk) {
    uint32_t bits = rand_bits(ks0, ks1, (uint32_t)cust * (uint32_t)KC + (uint32_t)k);
    float f = __uint_as_float((bits >> 9) | 0x3f800000u) - 1.0f;
    float u = (f > 0.0f) ? f : TINY;
    float g = -logf(-logf(u));
    v = g + x;
  }
  uint32_t uv = __float_as_uint(v);
  uint32_t key = (uv & 0x80000000u) ? ~uv : (uv | 0x80000000u);
  unsigned long long pk =
      ((unsigned long long)key << 32) | (uint32_t)(15 - k);  // ties -> min k
  float bwx = x;
  dpp_max_step<0xB1>(pk, bwx);
  dpp_max_step<0x4E>(pk, bwx);
  dpp_max_step<0x141>(pk, bwx);
  dpp_max_step<0x140>(pk, bwx);
  int best_k = 15 - (int)(pk & 0xFu);

  float xm = x;
  xm = dpp_fmax<0xB1>(xm); xm = dpp_fmax<0x4E>(xm);
  xm = dpp_fmax<0x141>(xm); xm = dpp_fmax<0x140>(xm);

  float es = actk ? expf(x - xm) : 0.0f;
  es = dpp_fadd<0xB1>(es); es = dpp_fadd<0x4E>(es);
  es = dpp_fadd<0x141>(es); es = dpp_fadd<0x140>(es);

  if (k == 0) {
    slp[cust] = (bwx - xm) - logf(es);
    assign[cust] = (uint8_t)best_k;
  }
}

// ---------------------------------------------------------------------------
// Kernel R v8 (r27 verbatim — session best, 28.42 us): one wave per block;
// four quad blocks per cluster (16-way route partition -> NN rounds = 1);
// blk 40 = lp reduction in 64 PARALLEL blocks (r28 proved single-block lp
// costs +11 us of serialized fetch).
// ---------------------------------------------------------------------------
__global__ __launch_bounds__(64, 1) void k_route(
    const float* __restrict__ coords,    // (64,1001,2)
    const float* __restrict__ demands,   // (64,1001)
    const float* __restrict__ capacity,  // (64,)
    const uint8_t* __restrict__ assign,  // (64,1000)
    const float* __restrict__ slp,       // (64,1000)
    double* __restrict__ pdistc,         // (64,10,4) per-(cluster,quad) sums
    double* __restrict__ lp) {           // (64,)
  int b = blockIdx.x / BPI;
  int blk = blockIdx.x % BPI;            // 0..39 = (cluster<<2)|quad, 40 = lp
  int lane = threadIdx.x;                // 0..63 (one wave)

  __shared__ float memx[MEMCAP], memy[MEMCAP], demp[MEMCAP];
  __shared__ uint16_t rsw[RCAP], rlw[RCAP];

  // ---- lp block: reduce slp[b] ----
  if (blk == 40) {
    const float4* s4 = reinterpret_cast<const float4*>(slp + (size_t)b * NC);
    double acc = 0.0;
#pragma unroll
    for (int t = 0; t < 4; ++t) {
      int idx = t * 64 + lane;
      if (idx < 250) {                   // 250 float4 = 1000 floats exactly
        float4 v = s4[idx];
        acc += (double)v.x + (double)v.y + (double)v.z + (double)v.w;
      }
    }
#pragma unroll
    for (int m = 1; m < 64; m <<= 1) acc += __shfl_xor(acc, m);
    if (lane == 0) lp[b] = acc;
    return;
  }

  int myk = blk >> 2;                    // cluster 0..9
  int qd  = blk & 3;                     // quad 0..3
  const float* cb = coords + (size_t)b * 1001 * 2;
  const float2* cb2 = reinterpret_cast<const float2*>(cb);
  const float* db = demands + (size_t)b * 1001;
  const uint8_t* ab = assign + (size_t)b * NC;
  float cap = capacity[b];
  float dx0 = cb[0], dy0 = cb[1];

  // ---- zero demp (padding correctness for the float4 split walk) ----
#pragma unroll
  for (int t = 0; t < 4; ++t) {
    int i = t * 64 + lane;
    if (i < MEMCAP) demp[i] = 0.0f;
  }

  // ---- wide-load compaction: lane owns customers 16*lane .. 16*lane+15 ----
  int ci0 = lane * 16;
  float X[16], Y[16], D[16];
  uint32_t A[16];
#pragma unroll
  for (int j = 0; j < 16; ++j) { X[j] = 0.0f; Y[j] = 0.0f; D[j] = 0.0f; A[j] = 0xFFu; }

  if (lane < 62) {
    const uint4* ap = reinterpret_cast<const uint4*>(ab + ci0);
    const float4* cp = reinterpret_cast<const float4*>(cb + 2 * ci0);
    const float4* dp = reinterpret_cast<const float4*>(db + ci0);
    uint4 a4 = ap[0];
    float4 c0 = cp[0], c1 = cp[1], c2 = cp[2], c3 = cp[3], c4 = cp[4],
           c5 = cp[5], c6 = cp[6], c7 = cp[7], c8 = cp[8];
    float4 e0 = dp[0], e1 = dp[1], e2 = dp[2], e3 = dp[3], e4 = dp[4];
    A[0]  =  a4.x        & 0xFFu; A[1]  = (a4.x >>  8) & 0xFFu;
    A[2]  = (a4.x >> 16) & 0xFFu; A[3]  = (a4.x >> 24) & 0xFFu;
    A[4]  =  a4.y        & 0xFFu; A[5]  = (a4.y >>  8) & 0xFFu;
    A[6]  = (a4.y >> 16) & 0xFFu; A[7]  = (a4.y >> 24) & 0xFFu;
    A[8]  =  a4.z        & 0xFFu; A[9]  = (a4.z >>  8) & 0xFFu;
    A[10] = (a4.z >> 16) & 0xFFu; A[11] = (a4.z >> 24) & 0xFFu;
    A[12] =  a4.w        & 0xFFu; A[13] = (a4.w >>  8) & 0xFFu;
    A[14] = (a4.w >> 16) & 0xFFu; A[15] = (a4.w >> 24) & 0xFFu;
    X[0]  = c0.z; Y[0]  = c0.w;  X[1]  = c1.x; Y[1]  = c1.y;
    X[2]  = c1.z; Y[2]  = c1.w;  X[3]  = c2.x; Y[3]  = c2.y;
    X[4]  = c2.z; Y[4]  = c2.w;  X[5]  = c3.x; Y[5]  = c3.y;
    X[6]  = c3.z; Y[6]  = c3.w;  X[7]  = c4.x; Y[7]  = c4.y;
    X[8]  = c4.z; Y[8]  = c4.w;  X[9]  = c5.x; Y[9]  = c5.y;
    X[10] = c5.z; Y[10] = c5.w;  X[11] = c6.x; Y[11] = c6.y;
    X[12] = c6.z; Y[12] = c6.w;  X[13] = c7.x; Y[13] = c7.y;
    X[14] = c7.z; Y[14] = c7.w;  X[15] = c8.x; Y[15] = c8.y;
    D[0]  = e0.y; D[1]  = e0.z; D[2]  = e0.w; D[3]  = e1.x;
    D[4]  = e1.y; D[5]  = e1.z; D[6]  = e1.w; D[7]  = e2.x;
    D[8]  = e2.y; D[9]  = e2.z; D[10] = e2.w; D[11] = e3.x;
    D[12] = e3.y; D[13] = e3.z; D[14] = e3.w; D[15] = e4.x;
  } else if (lane == 62) {
#pragma unroll
    for (int j = 0; j < 8; ++j) {
      int ci = 992 + j;
      A[j] = ab[ci];
      float2 c = cb2[ci + 1];
      X[j] = c.x; Y[j] = c.y;
      D[j] = db[ci + 1];
    }
  }

  // ---- rank: per-lane count + 6-step wave exclusive scan ----
  int cnt = 0;
#pragma unroll
  for (int j = 0; j < 16; ++j) cnt += (A[j] == (uint32_t)myk);
  int xs = cnt;
#pragma unroll
  for (int off = 1; off < 64; off <<= 1) {
    int v = __shfl_up(xs, off);
    if (lane >= off) xs += v;
  }
  int pos = xs - cnt;
  int mcount = __shfl(xs, 63);

  // ---- stable scatter (chunk-major = index order) ----
#pragma unroll
  for (int j = 0; j < 16; ++j) {
    if (A[j] == (uint32_t)myk && pos < MEMCAP) {
      memx[pos] = X[j];
      memy[pos] = Y[j];
      demp[pos] = D[j];
      pos++;
    }
  }
  int M = (mcount < MEMCAP) ? mcount : MEMCAP;

  // ---- capacity split: lane-0 float4 walk, 2-deep prefetch ----
  int rcount = 0;
  if (lane == 0 && M > 0) {
    const float4* dp4 = reinterpret_cast<const float4*>(&demp[0]);
    float load = 0.0f;
    int cur = 0, r = 0;
    int trips = (M + 3) >> 2;
    float4 cv = dp4[0];
    float4 nv = dp4[1];
    for (int t = 0; t < trips; ++t) {
      float4 nv2 = dp4[t + 2];
#define SPLIT_E(DV, E)                                                        \
      {                                                                       \
        int j = t * 4 + E;                                                    \
        float d = DV;                                                         \
        if (j == 0) load = d;                                                 \
        else if (load + d > cap) {                                            \
          rsw[r] = (uint16_t)cur; rlw[r] = (uint16_t)(j - cur);               \
          r++; cur = j; load = d;                                             \
        } else load += d;                /* padding d=0: load<=cap -> no-op */\
      }
      SPLIT_E(cv.x, 0) SPLIT_E(cv.y, 1) SPLIT_E(cv.z, 2) SPLIT_E(cv.w, 3)
#undef SPLIT_E
      cv = nv; nv = nv2;
    }
    rsw[r] = (uint16_t)cur;
    rlw[r] = (uint16_t)(M - cur);
    r++;
    rcount = r;
  }
  rcount = __shfl(rcount, 0);

  // ---- NN: this block handles routes r == qd*4 + grp (mod 16) ----
  int lane16 = lane & 15;
  int grp = lane >> 4;
  double gacc = 0.0;

  for (int r = qd * 4 + grp; r < rcount; r += 16) {
    int start = rsw[r];
    int L = rlw[r];
    float px = dx0, py = dy0, racc = 0.0f;

    if (L <= 16) {
      float mx = 0.0f, my = 0.0f;
      bool act = (lane16 < L);
      if (act) { mx = memx[start + lane16]; my = memy[start + lane16]; }
      uint32_t unv = act ? 1u : 0u;
      for (int step = 0; step < L; ++step) {
        float bd = INFINITY, bx = 0.0f, by = 0.0f;
        if (unv) {
          float ddx = mx - px, ddy = my - py;
          bd = sqrtf(ddx * ddx + ddy * ddy);
          bx = mx; by = my;
        }
        unsigned long long comb = unv
            ? ((((unsigned long long)__float_as_uint(bd)) << 32) |
               (unsigned)lane16)
            : ~0ull;
        dpp_min_step<0xB1>(comb, bx, by);
        dpp_min_step<0x4E>(comb, bx, by);
        dpp_min_step<0x141>(comb, bx, by);
        dpp_min_step<0x140>(comb, bx, by);
        int wl = (int)(comb & 0xFFFFFFFFull);
        float best = __uint_as_float((uint32_t)(comb >> 32));
        if (wl == (int)lane16) unv = 0;
        px = bx; py = by;
        racc += best;                    // f32, reference scan order
      }
    } else {
      float mx0 = 0, my0 = 0, mx1 = 0, my1 = 0, mx2 = 0, my2 = 0, mx3 = 0, my3 = 0;
      uint32_t vis = 0;
#define LOADC(c, MX, MY)                                                      \
      { int s = (c) * 16 + lane16;                                            \
        if (s < L) { MX = memx[start + s]; MY = memy[start + s]; }            \
        else vis |= (1u << (c)); }
      LOADC(0, mx0, my0) LOADC(1, mx1, my1) LOADC(2, mx2, my2) LOADC(3, mx3, my3)
#undef LOADC
      for (int step = 0; step < L; ++step) {
        float bd = INFINITY; int bc = -1; float bx = 0, by = 0;
#define CAND(c, MX, MY)                                                       \
        if (!(vis & (1u << (c)))) {                                           \
          float ddx = MX - px, ddy = MY - py;                                 \
          float d = sqrtf(ddx * ddx + ddy * ddy);                             \
          if (d < bd) { bd = d; bc = (c); bx = MX; by = MY; }                 \
        }
        CAND(0, mx0, my0) CAND(1, mx1, my1) CAND(2, mx2, my2) CAND(3, mx3, my3)
#undef CAND
        unsigned long long comb = (bc < 0)
            ? ~0ull
            : (((unsigned long long)__float_as_uint(bd)) << 32) |
              (unsigned)(bc * 16 + lane16);
        dpp_min_step<0xB1>(comb, bx, by);
        dpp_min_step<0x4E>(comb, bx, by);
        dpp_min_step<0x141>(comb, bx, by);
        dpp_min_step<0x140>(comb, bx, by);
        int slot = (int)(comb & 0xFFFFFFFFull);
        float best = __uint_as_float((uint32_t)(comb >> 32));
        int src16 = slot & 15, cu = slot >> 4;
        if (src16 == (int)lane16) vis |= (1u << cu);
        px = bx; py = by;
        racc += best;                    // f32, reference scan order
      }
    }
    float ddx = px - dx0, ddy = py - dy0;
    racc += sqrtf(ddx * ddx + ddy * ddy);
    gacc += (double)racc;
  }

  // ---- wave reduction of the group partials ----
  {
    double t2 = (lane16 == 0) ? gacc : 0.0;
#pragma unroll
    for (int m = 1; m < 64; m <<= 1) t2 += __shfl_xor(t2, m);
    if (lane == 0) pdistc[(b * KC + myk) * 4 + qd] = t2;
  }
}

// ---------------------------------------------------------------------------
// Kernel C (r27 verbatim): sums 40 (cluster,quad) partials per instance in
// fixed order + shfl loss math.
// ---------------------------------------------------------------------------
__global__ __launch_bounds__(64) void k_final(
    const double* __restrict__ pdistc,   // (64,10,4)
    const double* __restrict__ lp,       // (64,)
    float* __restrict__ out) {           // (2,)
  int tid = threadIdx.x;
  double dd = 0.0;
#pragma unroll
  for (int k = 0; k < KC * 4; ++k) dd += pdistc[tid * KC * 4 + k];
  float df = (float)dd;
  float lf = (float)lp[tid];
  double m = (double)df;
#pragma unroll
  for (int m2 = 1; m2 < 64; m2 <<= 1) m += __shfl_xor(m, m2);
  double mean = m / 64.0;
  float meanf = (float)mean;
  double li = ((double)df - (double)meanf) * (double)lf;
#pragma unroll
  for (int m2 = 1; m2 < 64; m2 <<= 1) li += __shfl_xor(li, m2);
  if (tid == 0) {
    out[0] = (float)(li / 64.0);
    out[1] = meanf;
  }
}

extern "C" void kernel_launch(void* const* d_in, const int* in_sizes, int n_in,
                              void* d_out, int out_size, void* d_ws, size_t ws_size,
                              hipStream_t stream) {
  const float* logits   = (const float*)d_in[0];  // (64,1001,10)
  const float* coords   = (const float*)d_in[1];  // (64,1001,2)
  const float* demands  = (const float*)d_in[2];  // (64,1001)
  const float* capacity = (const float*)d_in[3];  // (64,)

  uint8_t* ws = (uint8_t*)d_ws;
  double*  pdistc = (double*)(ws);            // 20480 B (64*10*4 doubles)
  double*  lp     = (double*)(ws + 20480);    // 512 B
  uint8_t* assign = (uint8_t*)(ws + 21504);   // 64000 B
  float*   slp    = (float*)(ws + 85504);     // 256000 B

  uint32_t ks0, ks1;
  threefry2x32(0u, 42u, 0u, 0u, &ks0, &ks1);   // fold_in(key(42), 0)

  k_sample<<<dim3(BB * NC * 16 / 256), dim3(256), 0, stream>>>(
      logits, ks0, ks1, assign, slp);
  k_route<<<dim3(BB * BPI), dim3(64), 0, stream>>>(
      coords, demands, capacity, assign, slp, pdistc, lp);
  k_final<<<dim3(1), dim3(64), 0, stream>>>(pdistc, lp, (float*)d_out);
}